// Round 5
// baseline (99.184 us; speedup 1.0000x reference)
//
#include <hip/hip_runtime.h>
#include <cstddef>
#include <cstdint>

#define S_LEN 2048
#define D_DIM 512
#define NHEAD 4
#define DHEAD 128
#define BH_CNT 16
#define SCALE_QK 0.08838834764831845f

typedef _Float16 f16;
typedef _Float16 f16x8 __attribute__((ext_vector_type(8)));
typedef float f32x16 __attribute__((ext_vector_type(16)));

#define AS1 __attribute__((address_space(1)))
#define AS3 __attribute__((address_space(3)))

__device__ __forceinline__ unsigned pkh(float a, float b) {
  auto r = __builtin_amdgcn_cvt_pkrtz(a, b);   // __fp16 ext_vector_type(2)
  return __builtin_bit_cast(unsigned, r);
}

// ---------------- Kernel 1: gate preactivations ----------------
__global__ __launch_bounds__(256) void gate_kernel(
    const float* __restrict__ q, const float* __restrict__ k, const float* __restrict__ v,
    const float* __restrict__ Wi, const float* __restrict__ bi,
    const float* __restrict__ Wf, const float* __restrict__ bf,
    float* __restrict__ ipre, float* __restrict__ fpre)
{
  const int wave = threadIdx.x >> 6;
  const int lane = threadIdx.x & 63;
  const int pos  = blockIdx.x * 4 + wave;
  const int b = pos >> 11;
  const int s = pos & 2047;
  const float* qp = q + (size_t)pos * D_DIM;
  const float* kp = k + (size_t)pos * D_DIM;
  const float* vp = v + (size_t)pos * D_DIM;

  float acc[8] = {0.f,0.f,0.f,0.f,0.f,0.f,0.f,0.f};
  #pragma unroll
  for (int j = 0; j < 24; ++j) {
    int e = lane + (j << 6);
    float x;
    if (e < 512)       x = qp[e];
    else if (e < 1024) x = kp[e - 512];
    else               x = vp[e - 1024];
    #pragma unroll
    for (int h = 0; h < 4; ++h) {
      acc[h]     = fmaf(x, Wi[h * 1536 + e], acc[h]);
      acc[4 + h] = fmaf(x, Wf[h * 1536 + e], acc[4 + h]);
    }
  }
  #pragma unroll
  for (int off = 32; off > 0; off >>= 1) {
    #pragma unroll
    for (int a = 0; a < 8; ++a) acc[a] += __shfl_down(acc[a], off);
  }
  if (lane == 0) {
    #pragma unroll
    for (int h = 0; h < 4; ++h) {
      ipre[(size_t)(b * 4 + h) * S_LEN + s] = acc[h] + bi[h];
      fpre[(size_t)(b * 4 + h) * S_LEN + s] = acc[4 + h] + bf[h];
    }
  }
}

// ---------------- Kernel 2: single-pass register scans ----------------
// 256 threads x 8 contiguous elems. bcum = cumsum(logsig(f)); g = i - bcum;
// M = cummax(g); Gt = per-64-tile max of g.
__global__ __launch_bounds__(256) void scan_kernel(
    const float* __restrict__ ipre, const float* __restrict__ fpre,
    float* __restrict__ g_out, float* __restrict__ M_out,
    float* __restrict__ bsum_out, float* __restrict__ Gt_out)
{
  __shared__ float wsh[8];
  const int bh = blockIdx.x;
  const int tid = threadIdx.x, lane = tid & 63, wv = tid >> 6;
  const int base = tid * 8;
  const float* fp = fpre + (size_t)bh * S_LEN;
  const float* ip = ipre + (size_t)bh * S_LEN;

  float x[8], ls[8];
  float4 a0 = *(const float4*)(fp + base), a1 = *(const float4*)(fp + base + 4);
  x[0]=a0.x; x[1]=a0.y; x[2]=a0.z; x[3]=a0.w;
  x[4]=a1.x; x[5]=a1.y; x[6]=a1.z; x[7]=a1.w;
  float run = 0.f;
  #pragma unroll
  for (int i = 0; i < 8; ++i) {
    float lsv = fminf(x[i], 0.f) - log1pf(expf(-fabsf(x[i])));
    run += lsv; ls[i] = run;
  }
  float sc = run;
  #pragma unroll
  for (int off = 1; off < 64; off <<= 1) {
    float o = __shfl_up(sc, off);
    if (lane >= off) sc += o;
  }
  if (lane == 63) wsh[wv] = sc;
  __syncthreads();
  float woff = 0.f;
  #pragma unroll
  for (int u = 0; u < 4; ++u) if (u < wv) woff += wsh[u];
  const float ex = woff + (sc - run);

  float4 i0 = *(const float4*)(ip + base), i1 = *(const float4*)(ip + base + 4);
  float iv[8];
  iv[0]=i0.x; iv[1]=i0.y; iv[2]=i0.z; iv[3]=i0.w;
  iv[4]=i1.x; iv[5]=i1.y; iv[6]=i1.z; iv[7]=i1.w;
  float g[8], bc[8], pm[8];
  float runm = -3.0e38f;
  #pragma unroll
  for (int i = 0; i < 8; ++i) {
    bc[i] = ex + ls[i];
    g[i] = iv[i] - bc[i];
    runm = fmaxf(runm, g[i]);
    pm[i] = runm;
  }
  *(float4*)(bsum_out + (size_t)bh * S_LEN + base)     = make_float4(bc[0],bc[1],bc[2],bc[3]);
  *(float4*)(bsum_out + (size_t)bh * S_LEN + base + 4) = make_float4(bc[4],bc[5],bc[6],bc[7]);
  *(float4*)(g_out + (size_t)bh * S_LEN + base)        = make_float4(g[0],g[1],g[2],g[3]);
  *(float4*)(g_out + (size_t)bh * S_LEN + base + 4)    = make_float4(g[4],g[5],g[6],g[7]);

  // Gt: 8 threads per 64-elem tile
  float t8 = runm;
  t8 = fmaxf(t8, __shfl_xor(t8, 1));
  t8 = fmaxf(t8, __shfl_xor(t8, 2));
  t8 = fmaxf(t8, __shfl_xor(t8, 4));
  if ((tid & 7) == 0) Gt_out[bh * 32 + (tid >> 3)] = t8;

  // cummax
  float scm = runm;
  #pragma unroll
  for (int off = 1; off < 64; off <<= 1) {
    float o = __shfl_up(scm, off);
    if (lane >= off) scm = fmaxf(scm, o);
  }
  if (lane == 63) wsh[4 + wv] = scm;
  __syncthreads();
  float wmo = -3.0e38f;
  #pragma unroll
  for (int u = 0; u < 4; ++u) if (u < wv) wmo = fmaxf(wmo, wsh[4 + u]);
  float prev = __shfl_up(scm, 1);
  if (lane == 0) prev = -3.0e38f;
  const float exm = fmaxf(wmo, prev);
  float M[8];
  #pragma unroll
  for (int i = 0; i < 8; ++i) M[i] = fmaxf(exm, pm[i]);
  *(float4*)(M_out + (size_t)bh * S_LEN + base)     = make_float4(M[0],M[1],M[2],M[3]);
  *(float4*)(M_out + (size_t)bh * S_LEN + base + 4) = make_float4(M[4],M[5],M[6],M[7]);
}

// ---------------- Kernel 3: fp16 conversion into MFMA-ready swizzled layouts ----
// qhat/khat: row-major rows of 256B (row s global), elem d at byte (2d)^((s&15)<<4)
// vT tile (bh,jt64): row d(128) x 128B, elem s at byte (2s)^((d&15)<<3)
__global__ __launch_bounds__(256) void convert_kernel(
    const float* __restrict__ q, const float* __restrict__ k, const float* __restrict__ v,
    const float* __restrict__ g_arr, const float* __restrict__ Gt_arr,
    char* __restrict__ qhat, char* __restrict__ khat, char* __restrict__ vT)
{
  const int it = blockIdx.x;     // 128-row tile index
  const int bh = blockIdx.y;
  const int b = bh >> 2, hh = bh & 3;
  const int tid = threadIdx.x;
  const size_t tb = (size_t)(bh * 16 + it) * 32768;
  const int rl = tid & 31, rg = tid >> 5;
  for (int j = 0; j < 16; ++j) {
    const int s = rg + 8 * j;
    const int sg = it * 128 + s;
    const float* qrow = q + ((size_t)(b * S_LEN + sg)) * D_DIM + hh * DHEAD;
    const float* krow = k + ((size_t)(b * S_LEN + sg)) * D_DIM + hh * DHEAD;
    float4 qv = *(const float4*)(qrow + rl * 4);
    float4 kv = *(const float4*)(krow + rl * 4);
    float cf = __expf(g_arr[(size_t)bh * S_LEN + sg] - Gt_arr[bh * 32 + (sg >> 6)]);
    uint2 qp, kp;
    qp.x = pkh(qv.x * SCALE_QK, qv.y * SCALE_QK);
    qp.y = pkh(qv.z * SCALE_QK, qv.w * SCALE_QK);
    kp.x = pkh(kv.x * cf, kv.y * cf);
    kp.y = pkh(kv.z * cf, kv.w * cf);
    const int off = (rl * 8) ^ ((s & 15) << 4);
    *(uint2*)(qhat + tb + s * 256 + off) = qp;
    *(uint2*)(khat + tb + s * 256 + off) = kp;
  }
  // V: two 64-row tiles per block
  const int d = tid & 127, oc = tid >> 7;
  const int swz8 = (d & 15) << 3;
  #pragma unroll
  for (int jt = 0; jt < 2; ++jt) {
    const size_t vtb = (size_t)(bh * 32 + it * 2 + jt) * 16384 + (size_t)d * 128;
    for (int j = 0; j < 4; ++j) {
      const int s0 = (oc + 2 * j) * 8;
      float vv[8];
      #pragma unroll
      for (int i = 0; i < 8; ++i)
        vv[i] = v[((size_t)(b * S_LEN + it * 128 + jt * 64 + s0 + i)) * D_DIM + hh * DHEAD + d];
      uint2 p0, p1;
      p0.x = pkh(vv[0], vv[1]); p0.y = pkh(vv[2], vv[3]);
      p1.x = pkh(vv[4], vv[5]); p1.y = pkh(vv[6], vv[7]);
      *(uint2*)(vT + vtb + ((2 * s0) ^ swz8))     = p0;
      *(uint2*)(vT + vtb + ((2 * s0 + 8) ^ swz8)) = p1;
    }
  }
}

// ---------------- Kernel 4: balanced MFMA attention ----------------
// 32-row q-tiles j in 0..63; block p processes pair (p, 63-p) -> uniform 33 steps.
// 4 waves: sh = s-half of the 64-col kt tile, dh = d-half for PV (QK duplicated).
__global__ __launch_bounds__(256, 2) void attn_kernel(
    const char* __restrict__ qhat, const char* __restrict__ khat, const char* __restrict__ vT,
    const float* __restrict__ M_arr, const float* __restrict__ bs_arr,
    const float* __restrict__ Gt_arr,
    const float* __restrict__ ln_w, const float* __restrict__ ln_b,
    float* __restrict__ out)
{
  __shared__ __align__(16) char smem[65536];   // buf c at c*32768: K 16K + V 16K
  const int p  = blockIdx.x;          // 0..31
  const int bh = blockIdx.y;
  const int b = bh >> 2, hh = bh & 3;
  const int tid = threadIdx.x;
  const int w = tid >> 6, lane = tid & 63, lo = lane & 31, hi = lane >> 5;
  const int sh = w & 1, dh = w >> 1;
  const int swz = (lo & 15) << 4;

  const char* gq = qhat + (size_t)bh * 524288;
  const char* gk = khat + (size_t)bh * 524288;
  const char* gv = vT   + (size_t)bh * 524288;
  const float* Mb  = M_arr  + (size_t)bh * S_LEN;
  const float* bsb = bs_arr + (size_t)bh * S_LEN;
  const float* Gtb = Gt_arr + bh * 32;

  for (int half = 0; half < 2; ++half) {
    const int j  = half ? (63 - p) : p;
    const int tg = 32 * j + lo;
    const float Mt = Mb[tg];
    const float em = __expf(-(bsb[tg] + Mt));
    const float M0 = Mb[32 * j];
    const int ktLast = (32 * j + 31) >> 6;
    int kts = 0;
    while (kts < ktLast && Gtb[kts] < M0 - 25.f) ++kts;

    // Q fragments direct from global (L2-resident, once per tile)
    f16x8 qf[8];
    const char* qrow = gq + (size_t)(32 * j + lo) * 256;
    #pragma unroll
    for (int ks = 0; ks < 8; ++ks)
      qf[ks] = *(const f16x8*)(qrow + ((ks * 32 + hi * 16) ^ swz));

    // stage first K/V into buf0
    {
      const char* gkt = gk + (size_t)kts * 16384;
      const char* gvt = gv + (size_t)kts * 16384;
      #pragma unroll
      for (int i = 0; i < 4; ++i) {
        int off = (i * 256 + tid) * 16;
        __builtin_amdgcn_global_load_lds((const AS1 void*)(gkt + off), (AS3 void*)(smem + off), 16, 0, 0);
        __builtin_amdgcn_global_load_lds((const AS1 void*)(gvt + off), (AS3 void*)(smem + 16384 + off), 16, 0, 0);
      }
    }
    asm volatile("s_waitcnt vmcnt(0)" ::: "memory");
    __syncthreads();

    f32x16 h0 = {}, h1 = {};
    float rowsum = 0.f;
    int cur = 0;
    for (int kt = kts; kt <= ktLast; ++kt) {
      if (kt < ktLast) {
        char* lb = smem + (cur ^ 1) * 32768;
        const char* gkt = gk + (size_t)(kt + 1) * 16384;
        const char* gvt = gv + (size_t)(kt + 1) * 16384;
        #pragma unroll
        for (int i = 0; i < 4; ++i) {
          int off = (i * 256 + tid) * 16;
          __builtin_amdgcn_global_load_lds((const AS1 void*)(gkt + off), (AS3 void*)(lb + off), 16, 0, 0);
          __builtin_amdgcn_global_load_lds((const AS1 void*)(gvt + off), (AS3 void*)(lb + 16384 + off), 16, 0, 0);
        }
      }
      const float dM = Gtb[kt] - Mt;
      if (__any(dM >= -25.f)) {
        const float rf = __expf(dM);
        const char* kb  = smem + cur * 32768;
        const char* vbp = kb + 16384;
        // QK^T (duplicated across dh): wave's 32s x 32t tile
        f32x16 sacc = {};
        const char* krow = kb + (32 * sh + lo) * 256;
        #pragma unroll
        for (int ks = 0; ks < 8; ++ks) {
          f16x8 a = *(const f16x8*)(krow + ((ks * 32 + hi * 16) ^ swz));
          sacc = __builtin_amdgcn_mfma_f32_32x32x16_f16(a, qf[ks], sacc, 0, 0, 0);
        }
        const int bnd = 32 * j + lo - 64 * kt;   // mask s-local > bnd
        float vals[16];
        float tsum = 0.f;
        #pragma unroll
        for (int r = 0; r < 16; ++r) {
          float val = sacc[r] * rf;
          int sl = 32 * sh + (r & 3) + 8 * (r >> 2) + 4 * hi;
          if (sl > bnd) val = 0.f;
          tsum += val;
          vals[r] = val;
        }
        rowsum += tsum + __shfl_xor(tsum, 32);
        uint32_t a0 = pkh(vals[0], vals[1]),   a1 = pkh(vals[2], vals[3]);
        uint32_t a2 = pkh(vals[4], vals[5]),   a3 = pkh(vals[6], vals[7]);
        uint32_t b0 = pkh(vals[8], vals[9]),   b1 = pkh(vals[10], vals[11]);
        uint32_t b2 = pkh(vals[12], vals[13]), b3 = pkh(vals[14], vals[15]);
        uint32_t sa0 = __shfl_xor(a0, 32), sa1 = __shfl_xor(a1, 32);
        uint32_t sa2 = __shfl_xor(a2, 32), sa3 = __shfl_xor(a3, 32);
        uint32_t sb0 = __shfl_xor(b0, 32), sb1 = __shfl_xor(b1, 32);
        uint32_t sb2 = __shfl_xor(b2, 32), sb3 = __shfl_xor(b3, 32);
        uint4 f0, f1;
        f0.x = hi ? sa2 : a0;  f0.y = hi ? sa3 : a1;
        f0.z = hi ? a2 : sa0;  f0.w = hi ? a3 : sa1;
        f1.x = hi ? sb2 : b0;  f1.y = hi ? sb3 : b1;
        f1.z = hi ? b2 : sb0;  f1.w = hi ? b3 : sb1;
        // PV: this wave's 2 d-blocks over its 32-s block
        #pragma unroll
        for (int dfi = 0; dfi < 2; ++dfi) {
          const int d = 32 * (2 * dh + dfi) + lo;
          const char* vrow = vbp + d * 128;
          const int swzv = (d & 15) << 3;
          #pragma unroll
          for (int ks2 = 0; ks2 < 2; ++ks2) {
            const int xx = sh * 64 + ks2 * 32 + hi * 16;
            uint2 p0 = *(const uint2*)(vrow + (xx ^ swzv));
            uint2 p1 = *(const uint2*)(vrow + ((xx + 8) ^ swzv));
            uint4 av; av.x = p0.x; av.y = p0.y; av.z = p1.x; av.w = p1.y;
            f16x8 a = __builtin_bit_cast(f16x8, av);
            f16x8 pp = __builtin_bit_cast(f16x8, ks2 ? f1 : f0);
            if (dfi) h1 = __builtin_amdgcn_mfma_f32_32x32x16_f16(a, pp, h1, 0, 0, 0);
            else     h0 = __builtin_amdgcn_mfma_f32_32x32x16_f16(a, pp, h0, 0, 0, 0);
          }
        }
      }
      asm volatile("s_waitcnt vmcnt(0)" ::: "memory");
      __syncthreads();
      cur ^= 1;
    }

    // ---- combine s-halves + epilogue ----
    float* cb = (float*)smem;
    if (sh == 1) {
      #pragma unroll
      for (int r = 0; r < 16; ++r) {
        cb[(dh * 2 + 0) * 1024 + r * 64 + lane] = h0[r];
        cb[(dh * 2 + 1) * 1024 + r * 64 + lane] = h1[r];
      }
      if (dh == 0) cb[4096 + lane] = rowsum;
    }
    __syncthreads();
    float s1 = 0.f, s2 = 0.f;
    float invn = 0.f;
    if (sh == 0) {
      #pragma unroll
      for (int r = 0; r < 16; ++r) {
        h0[r] += cb[(dh * 2 + 0) * 1024 + r * 64 + lane];
        h1[r] += cb[(dh * 2 + 1) * 1024 + r * 64 + lane];
      }
      rowsum += cb[4096 + lane];
      float n = fmaxf(fabsf(rowsum), em);
      invn = 1.f / (n + 5e-5f);
      #pragma unroll
      for (int r = 0; r < 16; ++r) {
        float x0 = h0[r] * invn, x1 = h1[r] * invn;
        h0[r] = x0; h1[r] = x1;
        s1 += x0 + x1; s2 += x0 * x0 + x1 * x1;
      }
      s1 += __shfl_xor(s1, 32);
      s2 += __shfl_xor(s2, 32);
      cb[4160 + dh * 64 + lane] = s1;
      cb[4288 + dh * 64 + lane] = s2;
    }
    __syncthreads();
    if (sh == 0) {
      s1 += cb[4160 + (dh ^ 1) * 64 + lane];
      s2 += cb[4288 + (dh ^ 1) * 64 + lane];
      float mu = s1 * (1.f / 128.f);
      float var = s2 * (1.f / 128.f) - mu * mu;
      float rstd = rsqrtf(var + 1e-3f);
      float* orow = out + ((size_t)(b * S_LEN) + tg) * D_DIM + hh * DHEAD;
      #pragma unroll
      for (int dfi = 0; dfi < 2; ++dfi) {
        #pragma unroll
        for (int rq = 0; rq < 4; ++rq) {
          int dbase = 32 * (2 * dh + dfi) + 8 * rq + 4 * hi;
          float4 wv = *(const float4*)(ln_w + hh * DHEAD + dbase);
          float4 bv = *(const float4*)(ln_b + hh * DHEAD + dbase);
          float4 o;
          float v0 = dfi ? h1[rq * 4 + 0] : h0[rq * 4 + 0];
          float v1 = dfi ? h1[rq * 4 + 1] : h0[rq * 4 + 1];
          float v2 = dfi ? h1[rq * 4 + 2] : h0[rq * 4 + 2];
          float v3 = dfi ? h1[rq * 4 + 3] : h0[rq * 4 + 3];
          o.x = (v0 - mu) * rstd * (1.f + wv.x) + bv.x;
          o.y = (v1 - mu) * rstd * (1.f + wv.y) + bv.y;
          o.z = (v2 - mu) * rstd * (1.f + wv.z) + bv.z;
          o.w = (v3 - mu) * rstd * (1.f + wv.w) + bv.w;
          *(float4*)(orow + dbase) = o;
        }
      }
    }
    __syncthreads();   // cb region reused as staging buffer next tile
  }
}

extern "C" void kernel_launch(void* const* d_in, const int* in_sizes, int n_in,
                              void* d_out, int out_size, void* d_ws, size_t ws_size,
                              hipStream_t stream) {
  (void)in_sizes; (void)n_in; (void)out_size; (void)ws_size;
  const float* q    = (const float*)d_in[0];
  const float* k    = (const float*)d_in[1];
  const float* v    = (const float*)d_in[2];
  const float* Wi   = (const float*)d_in[3];
  const float* bi   = (const float*)d_in[4];
  const float* Wf   = (const float*)d_in[5];
  const float* bf   = (const float*)d_in[6];
  const float* ln_w = (const float*)d_in[7];
  const float* ln_b = (const float*)d_in[8];

  char* wsb = (char*)d_ws;
  float* ipre = (float*)(wsb + 0);
  float* fpre = (float*)(wsb + 131072);
  float* garr = (float*)(wsb + 262144);
  float* Marr = (float*)(wsb + 393216);
  float* bsum = (float*)(wsb + 524288);
  float* Gt   = (float*)(wsb + 655360);       // 16*32 floats
  char* qh = wsb + 1048576;
  char* kh = wsb + 1048576 + 8388608;
  char* vt = wsb + 1048576 + 16777216;

  gate_kernel<<<2048, 256, 0, stream>>>(q, k, v, Wi, bi, Wf, bf, ipre, fpre);
  scan_kernel<<<16, 256, 0, stream>>>(ipre, fpre, garr, Marr, bsum, Gt);
  convert_kernel<<<dim3(16, 16), 256, 0, stream>>>(q, k, v, garr, Gt, qh, kh, vt);
  attn_kernel<<<dim3(32, 16), 256, 0, stream>>>(qh, kh, vt, Marr, bsum, Gt,
                                                ln_w, ln_b, (float*)d_out);
}

// Round 6
// 96.351 us; speedup vs baseline: 1.0294x; 1.0294x over previous
//
#include <hip/hip_runtime.h>
#include <cstddef>
#include <cstdint>

#define S_LEN 2048
#define D_DIM 512
#define NHEAD 4
#define DHEAD 128
#define BH_CNT 16
#define SCALE_QK 0.08838834764831845f

typedef _Float16 f16;
typedef _Float16 f16x8 __attribute__((ext_vector_type(8)));
typedef float f32x16 __attribute__((ext_vector_type(16)));

#define AS1 __attribute__((address_space(1)))
#define AS3 __attribute__((address_space(3)))

__device__ __forceinline__ unsigned pkh(float a, float b) {
  auto r = __builtin_amdgcn_cvt_pkrtz(a, b);   // __fp16 ext_vector_type(2)
  return __builtin_bit_cast(unsigned, r);
}

// ---------------- Kernel 1: gate preactivations ----------------
__global__ __launch_bounds__(256) void gate_kernel(
    const float* __restrict__ q, const float* __restrict__ k, const float* __restrict__ v,
    const float* __restrict__ Wi, const float* __restrict__ bi,
    const float* __restrict__ Wf, const float* __restrict__ bf,
    float* __restrict__ ipre, float* __restrict__ fpre)
{
  const int wave = threadIdx.x >> 6;
  const int lane = threadIdx.x & 63;
  const int pos  = blockIdx.x * 4 + wave;
  const int b = pos >> 11;
  const int s = pos & 2047;
  const float* qp = q + (size_t)pos * D_DIM;
  const float* kp = k + (size_t)pos * D_DIM;
  const float* vp = v + (size_t)pos * D_DIM;

  float acc[8] = {0.f,0.f,0.f,0.f,0.f,0.f,0.f,0.f};
  #pragma unroll
  for (int j = 0; j < 24; ++j) {
    int e = lane + (j << 6);
    float x;
    if (e < 512)       x = qp[e];
    else if (e < 1024) x = kp[e - 512];
    else               x = vp[e - 1024];
    #pragma unroll
    for (int h = 0; h < 4; ++h) {
      acc[h]     = fmaf(x, Wi[h * 1536 + e], acc[h]);
      acc[4 + h] = fmaf(x, Wf[h * 1536 + e], acc[4 + h]);
    }
  }
  #pragma unroll
  for (int off = 32; off > 0; off >>= 1) {
    #pragma unroll
    for (int a = 0; a < 8; ++a) acc[a] += __shfl_down(acc[a], off);
  }
  if (lane == 0) {
    #pragma unroll
    for (int h = 0; h < 4; ++h) {
      ipre[(size_t)(b * 4 + h) * S_LEN + s] = acc[h] + bi[h];
      fpre[(size_t)(b * 4 + h) * S_LEN + s] = acc[4 + h] + bf[h];
    }
  }
}

// ---------------- Kernel 2: single-pass register scans ----------------
__global__ __launch_bounds__(256) void scan_kernel(
    const float* __restrict__ ipre, const float* __restrict__ fpre,
    float* __restrict__ g_out, float* __restrict__ M_out,
    float* __restrict__ bsum_out, float* __restrict__ Gt_out)
{
  __shared__ float wsh[8];
  const int bh = blockIdx.x;
  const int tid = threadIdx.x, lane = tid & 63, wv = tid >> 6;
  const int base = tid * 8;
  const float* fp = fpre + (size_t)bh * S_LEN;
  const float* ip = ipre + (size_t)bh * S_LEN;

  float x[8], ls[8];
  float4 a0 = *(const float4*)(fp + base), a1 = *(const float4*)(fp + base + 4);
  x[0]=a0.x; x[1]=a0.y; x[2]=a0.z; x[3]=a0.w;
  x[4]=a1.x; x[5]=a1.y; x[6]=a1.z; x[7]=a1.w;
  float run = 0.f;
  #pragma unroll
  for (int i = 0; i < 8; ++i) {
    float lsv = fminf(x[i], 0.f) - log1pf(expf(-fabsf(x[i])));
    run += lsv; ls[i] = run;
  }
  float sc = run;
  #pragma unroll
  for (int off = 1; off < 64; off <<= 1) {
    float o = __shfl_up(sc, off);
    if (lane >= off) sc += o;
  }
  if (lane == 63) wsh[wv] = sc;
  __syncthreads();
  float woff = 0.f;
  #pragma unroll
  for (int u = 0; u < 4; ++u) if (u < wv) woff += wsh[u];
  const float ex = woff + (sc - run);

  float4 i0 = *(const float4*)(ip + base), i1 = *(const float4*)(ip + base + 4);
  float iv[8];
  iv[0]=i0.x; iv[1]=i0.y; iv[2]=i0.z; iv[3]=i0.w;
  iv[4]=i1.x; iv[5]=i1.y; iv[6]=i1.z; iv[7]=i1.w;
  float g[8], bc[8], pm[8];
  float runm = -3.0e38f;
  #pragma unroll
  for (int i = 0; i < 8; ++i) {
    bc[i] = ex + ls[i];
    g[i] = iv[i] - bc[i];
    runm = fmaxf(runm, g[i]);
    pm[i] = runm;
  }
  *(float4*)(bsum_out + (size_t)bh * S_LEN + base)     = make_float4(bc[0],bc[1],bc[2],bc[3]);
  *(float4*)(bsum_out + (size_t)bh * S_LEN + base + 4) = make_float4(bc[4],bc[5],bc[6],bc[7]);
  *(float4*)(g_out + (size_t)bh * S_LEN + base)        = make_float4(g[0],g[1],g[2],g[3]);
  *(float4*)(g_out + (size_t)bh * S_LEN + base + 4)    = make_float4(g[4],g[5],g[6],g[7]);

  // Gt: 8 threads per 64-elem tile
  float t8 = runm;
  t8 = fmaxf(t8, __shfl_xor(t8, 1));
  t8 = fmaxf(t8, __shfl_xor(t8, 2));
  t8 = fmaxf(t8, __shfl_xor(t8, 4));
  if ((tid & 7) == 0) Gt_out[bh * 32 + (tid >> 3)] = t8;

  // cummax
  float scm = runm;
  #pragma unroll
  for (int off = 1; off < 64; off <<= 1) {
    float o = __shfl_up(scm, off);
    if (lane >= off) scm = fmaxf(scm, o);
  }
  if (lane == 63) wsh[4 + wv] = scm;
  __syncthreads();
  float wmo = -3.0e38f;
  #pragma unroll
  for (int u = 0; u < 4; ++u) if (u < wv) wmo = fmaxf(wmo, wsh[4 + u]);
  float prev = __shfl_up(scm, 1);
  if (lane == 0) prev = -3.0e38f;
  const float exm = fmaxf(wmo, prev);
  float M[8];
  #pragma unroll
  for (int i = 0; i < 8; ++i) M[i] = fmaxf(exm, pm[i]);
  *(float4*)(M_out + (size_t)bh * S_LEN + base)     = make_float4(M[0],M[1],M[2],M[3]);
  *(float4*)(M_out + (size_t)bh * S_LEN + base + 4) = make_float4(M[4],M[5],M[6],M[7]);
}

// ---------------- Kernel 3: plain fp16 conversion (no gating folded) ----------
// khat: global row s x 256B, elem d at byte (2d)^((s&15)<<4)
// vT tile (bh,jt64): row d(128) x 128B, elem s at byte (2s)^((d&15)<<3)
__global__ __launch_bounds__(256) void convert_kernel(
    const float* __restrict__ k, const float* __restrict__ v,
    char* __restrict__ khat, char* __restrict__ vT)
{
  const int it = blockIdx.x;     // 128-row tile index
  const int bh = blockIdx.y;
  const int b = bh >> 2, hh = bh & 3;
  const int tid = threadIdx.x;
  const size_t tb = (size_t)(bh * 16 + it) * 32768;
  const int rl = tid & 31, rg = tid >> 5;
  for (int j = 0; j < 16; ++j) {
    const int s = rg + 8 * j;
    const int sg = it * 128 + s;
    const float* krow = k + ((size_t)(b * S_LEN + sg)) * D_DIM + hh * DHEAD;
    float4 kv = *(const float4*)(krow + rl * 4);
    uint2 kp;
    kp.x = pkh(kv.x, kv.y);
    kp.y = pkh(kv.z, kv.w);
    const int off = (rl * 8) ^ ((s & 15) << 4);
    *(uint2*)(khat + tb + s * 256 + off) = kp;
  }
  const int d = tid & 127, oc = tid >> 7;
  const int swz8 = (d & 15) << 3;
  #pragma unroll
  for (int jt = 0; jt < 2; ++jt) {
    const size_t vtb = (size_t)(bh * 32 + it * 2 + jt) * 16384 + (size_t)d * 128;
    for (int j = 0; j < 4; ++j) {
      const int s0 = (oc + 2 * j) * 8;
      float vv[8];
      #pragma unroll
      for (int i = 0; i < 8; ++i)
        vv[i] = v[((size_t)(b * S_LEN + it * 128 + jt * 64 + s0 + i)) * D_DIM + hh * DHEAD + d];
      uint2 p0, p1;
      p0.x = pkh(vv[0], vv[1]); p0.y = pkh(vv[2], vv[3]);
      p1.x = pkh(vv[4], vv[5]); p1.y = pkh(vv[6], vv[7]);
      *(uint2*)(vT + vtb + ((2 * s0) ^ swz8))     = p0;
      *(uint2*)(vT + vtb + ((2 * s0 + 8) ^ swz8)) = p1;
    }
  }
}

// ---------------- Kernel 4: balanced 8-wave MFMA attention ----------------
// 64-row q-tiles j in 0..31 per bh; block (bh, p) processes (31-p, p): 33 steps.
// blockIdx.x = bh so all blocks of one bh share an XCD's L2 (K/V stream 1 MB).
// Waves: th = t-half(32), sh = s-half(32), dh = d-half(64). QK dup across dh.
// Decay: cf=exp(g[s]-Gt) scales K A-frag per lane; rf=exp(Gt-Mt) post-MFMA.
__global__ __launch_bounds__(512, 2) void attn_kernel(
    const float* __restrict__ q, const char* __restrict__ khat, const char* __restrict__ vT,
    const float* __restrict__ g_arr, const float* __restrict__ M_arr,
    const float* __restrict__ bs_arr, const float* __restrict__ Gt_arr,
    const float* __restrict__ ln_w, const float* __restrict__ ln_b,
    float* __restrict__ out)
{
  __shared__ __align__(16) char smem[65536];   // buf c at c*32768: K 16K + V 16K
  const int bh = blockIdx.x;          // XCD grouping: flat id % 8 == bh % 8
  const int p  = blockIdx.y;          // 0..15
  const int b = bh >> 2, hh = bh & 3;
  const int tid = threadIdx.x;
  const int w = tid >> 6, lane = tid & 63, lo = lane & 31, hi = lane >> 5;
  const int th = w & 1, sh = (w >> 1) & 1, dh = w >> 2;
  const int swz = (lo & 15) << 4;
  const int tl = 32 * th + lo;        // t-local in 64-row tile

  const char* gk = khat + (size_t)bh * 524288;
  const char* gv = vT   + (size_t)bh * 524288;
  const float* Mb  = M_arr  + (size_t)bh * S_LEN;
  const float* bsb = bs_arr + (size_t)bh * S_LEN;
  const float* gb  = g_arr  + (size_t)bh * S_LEN;
  const float* Gtb = Gt_arr + bh * 32;

  for (int half = 0; half < 2; ++half) {
    const int j  = half ? p : (31 - p);
    const int tg = 64 * j + tl;
    const float Mt = Mb[tg];
    const float em = __expf(-(bsb[tg] + Mt));
    const float M0 = Mb[64 * j];
    int kts = 0;
    while (kts < j && Gtb[kts] < M0 - 25.f) ++kts;

    // Q fragments straight from fp32 global (once per tile)
    f16x8 qf[8];
    const float* qrow = q + ((size_t)(b * S_LEN + tg)) * D_DIM + hh * DHEAD;
    #pragma unroll
    for (int ks = 0; ks < 8; ++ks) {
      const int d0 = ks * 16 + hi * 8;
      float4 x0 = *(const float4*)(qrow + d0);
      float4 x1 = *(const float4*)(qrow + d0 + 4);
      uint4 u;
      u.x = pkh(x0.x * SCALE_QK, x0.y * SCALE_QK);
      u.y = pkh(x0.z * SCALE_QK, x0.w * SCALE_QK);
      u.z = pkh(x1.x * SCALE_QK, x1.y * SCALE_QK);
      u.w = pkh(x1.z * SCALE_QK, x1.w * SCALE_QK);
      qf[ks] = __builtin_bit_cast(f16x8, u);
    }

    __syncthreads();   // prev epilogue LDS reads done before restaging
    {
      const char* gkt = gk + (size_t)kts * 16384;
      const char* gvt = gv + (size_t)kts * 16384;
      #pragma unroll
      for (int i = 0; i < 2; ++i) {
        int off = (i * 512 + tid) * 16;
        __builtin_amdgcn_global_load_lds((const AS1 void*)(gkt + off), (AS3 void*)(smem + off), 16, 0, 0);
        __builtin_amdgcn_global_load_lds((const AS1 void*)(gvt + off), (AS3 void*)(smem + 16384 + off), 16, 0, 0);
      }
    }
    asm volatile("s_waitcnt vmcnt(0)" ::: "memory");
    __syncthreads();

    f32x16 h0 = {}, h1 = {};
    float rowsum = 0.f;
    int cur = 0;
    for (int kt = kts; kt <= j; ++kt) {
      if (kt < j) {
        char* lb = smem + (cur ^ 1) * 32768;
        const char* gkt = gk + (size_t)(kt + 1) * 16384;
        const char* gvt = gv + (size_t)(kt + 1) * 16384;
        #pragma unroll
        for (int i = 0; i < 2; ++i) {
          int off = (i * 512 + tid) * 16;
          __builtin_amdgcn_global_load_lds((const AS1 void*)(gkt + off), (AS3 void*)(lb + off), 16, 0, 0);
          __builtin_amdgcn_global_load_lds((const AS1 void*)(gvt + off), (AS3 void*)(lb + 16384 + off), 16, 0, 0);
        }
      }
      const float Gtv = Gtb[kt];
      const float dM = Gtv - Mt;
      if (__any(dM >= -25.f)) {
        const float rf = __expf(dM);
        const char* kb  = smem + cur * 32768;
        const char* vbp = kb + 16384;
        // decay for this lane's K row s = 32*sh + lo
        const float cf = __expf(gb[64 * kt + 32 * sh + lo] - Gtv);
        const _Float16 cfh = (_Float16)cf;
        // QK^T (dup across dh): A = K rows (s), B = Q cols (t)
        f32x16 sacc = {};
        const char* krow = kb + (32 * sh + lo) * 256;
        #pragma unroll
        for (int ks = 0; ks < 8; ++ks) {
          f16x8 a = *(const f16x8*)(krow + ((ks * 32 + hi * 16) ^ swz));
          a = a * cfh;
          sacc = __builtin_amdgcn_mfma_f32_32x32x16_f16(a, qf[ks], sacc, 0, 0, 0);
        }
        float vals[16];
        float tsum = 0.f;
        #pragma unroll
        for (int r = 0; r < 16; ++r) {
          float val = sacc[r] * rf;
          if (kt == j) {
            int sl = 32 * sh + (r & 3) + 8 * (r >> 2) + 4 * hi;
            if (sl > tl) val = 0.f;
          }
          tsum += val;
          vals[r] = val;
        }
        rowsum += tsum + __shfl_xor(tsum, 32);
        uint32_t a0 = pkh(vals[0], vals[1]),   a1 = pkh(vals[2], vals[3]);
        uint32_t a2 = pkh(vals[4], vals[5]),   a3 = pkh(vals[6], vals[7]);
        uint32_t b0 = pkh(vals[8], vals[9]),   b1 = pkh(vals[10], vals[11]);
        uint32_t b2 = pkh(vals[12], vals[13]), b3 = pkh(vals[14], vals[15]);
        uint32_t sa0 = __shfl_xor(a0, 32), sa1 = __shfl_xor(a1, 32);
        uint32_t sa2 = __shfl_xor(a2, 32), sa3 = __shfl_xor(a3, 32);
        uint32_t sb0 = __shfl_xor(b0, 32), sb1 = __shfl_xor(b1, 32);
        uint32_t sb2 = __shfl_xor(b2, 32), sb3 = __shfl_xor(b3, 32);
        uint4 f0, f1;
        f0.x = hi ? sa2 : a0;  f0.y = hi ? sa3 : a1;
        f0.z = hi ? a2 : sa0;  f0.w = hi ? a3 : sa1;
        f1.x = hi ? sb2 : b0;  f1.y = hi ? sb3 : b1;
        f1.z = hi ? b2 : sb0;  f1.w = hi ? b3 : sb1;
        // PV: this wave's d-half (2 blocks of 32) over its s-half
        #pragma unroll
        for (int dfi = 0; dfi < 2; ++dfi) {
          const int d = 64 * dh + 32 * dfi + lo;
          const char* vrow = vbp + d * 128;
          const int swzv = (d & 15) << 3;
          #pragma unroll
          for (int ks2 = 0; ks2 < 2; ++ks2) {
            const int xx = sh * 64 + ks2 * 32 + hi * 16;
            uint2 p0 = *(const uint2*)(vrow + (xx ^ swzv));
            uint2 p1 = *(const uint2*)(vrow + ((xx + 8) ^ swzv));
            uint4 av; av.x = p0.x; av.y = p0.y; av.z = p1.x; av.w = p1.y;
            f16x8 a = __builtin_bit_cast(f16x8, av);
            f16x8 pp = __builtin_bit_cast(f16x8, ks2 ? f1 : f0);
            if (dfi) h1 = __builtin_amdgcn_mfma_f32_32x32x16_f16(a, pp, h1, 0, 0, 0);
            else     h0 = __builtin_amdgcn_mfma_f32_32x32x16_f16(a, pp, h0, 0, 0, 0);
          }
        }
      }
      asm volatile("s_waitcnt vmcnt(0)" ::: "memory");
      __syncthreads();
      cur ^= 1;
    }

    // ---- epilogue: combine s-halves, n, cross-dh LN stats, store ----
    float* sf = (float*)smem;
    const int fbase = (th * 2 + dh) * 2048;
    if (sh == 1) {
      #pragma unroll
      for (int r = 0; r < 16; ++r) {
        sf[fbase + r * 64 + lane]        = h0[r];
        sf[fbase + 1024 + r * 64 + lane] = h1[r];
      }
      if (dh == 0 && hi == 0) sf[8192 + tl] = rowsum;
    }
    __syncthreads();
    float s1 = 0.f, s2 = 0.f;
    if (sh == 0) {
      #pragma unroll
      for (int r = 0; r < 16; ++r) {
        h0[r] += sf[fbase + r * 64 + lane];
        h1[r] += sf[fbase + 1024 + r * 64 + lane];
      }
      rowsum += sf[8192 + tl];
      float n = fmaxf(fabsf(rowsum), em);
      float invn = 1.f / (n + 5e-5f);
      #pragma unroll
      for (int r = 0; r < 16; ++r) {
        float x0 = h0[r] * invn, x1 = h1[r] * invn;
        h0[r] = x0; h1[r] = x1;
        s1 += x0 + x1; s2 += x0 * x0 + x1 * x1;
      }
      s1 += __shfl_xor(s1, 32);
      s2 += __shfl_xor(s2, 32);
      sf[8320 + dh * 64 + tl] = s1;
      sf[8448 + dh * 64 + tl] = s2;
    }
    __syncthreads();
    if (sh == 0) {
      s1 += sf[8320 + (dh ^ 1) * 64 + tl];
      s2 += sf[8448 + (dh ^ 1) * 64 + tl];
      float mu = s1 * (1.f / 128.f);
      float var = s2 * (1.f / 128.f) - mu * mu;
      float rstd = rsqrtf(var + 1e-3f);
      float* orow = out + ((size_t)(b * S_LEN) + tg) * D_DIM + hh * DHEAD;
      #pragma unroll
      for (int dfi = 0; dfi < 2; ++dfi) {
        #pragma unroll
        for (int rq = 0; rq < 4; ++rq) {
          int dbase = 64 * dh + 32 * dfi + 8 * rq + 4 * hi;
          float4 wv = *(const float4*)(ln_w + hh * DHEAD + dbase);
          float4 bv = *(const float4*)(ln_b + hh * DHEAD + dbase);
          float v0 = dfi ? h1[rq * 4 + 0] : h0[rq * 4 + 0];
          float v1 = dfi ? h1[rq * 4 + 1] : h0[rq * 4 + 1];
          float v2 = dfi ? h1[rq * 4 + 2] : h0[rq * 4 + 2];
          float v3 = dfi ? h1[rq * 4 + 3] : h0[rq * 4 + 3];
          float4 o;
          o.x = (v0 - mu) * rstd * (1.f + wv.x) + bv.x;
          o.y = (v1 - mu) * rstd * (1.f + wv.y) + bv.y;
          o.z = (v2 - mu) * rstd * (1.f + wv.z) + bv.z;
          o.w = (v3 - mu) * rstd * (1.f + wv.w) + bv.w;
          *(float4*)(orow + dbase) = o;
        }
      }
    }
  }
}

extern "C" void kernel_launch(void* const* d_in, const int* in_sizes, int n_in,
                              void* d_out, int out_size, void* d_ws, size_t ws_size,
                              hipStream_t stream) {
  (void)in_sizes; (void)n_in; (void)out_size; (void)ws_size;
  const float* q    = (const float*)d_in[0];
  const float* k    = (const float*)d_in[1];
  const float* v    = (const float*)d_in[2];
  const float* Wi   = (const float*)d_in[3];
  const float* bi   = (const float*)d_in[4];
  const float* Wf   = (const float*)d_in[5];
  const float* bf   = (const float*)d_in[6];
  const float* ln_w = (const float*)d_in[7];
  const float* ln_b = (const float*)d_in[8];

  char* wsb = (char*)d_ws;
  float* ipre = (float*)(wsb + 0);
  float* fpre = (float*)(wsb + 131072);
  float* garr = (float*)(wsb + 262144);
  float* Marr = (float*)(wsb + 393216);
  float* bsum = (float*)(wsb + 524288);
  float* Gt   = (float*)(wsb + 655360);       // 16*32 floats
  char* kh = wsb + 1048576;
  char* vt = wsb + 1048576 + 8388608;

  gate_kernel<<<2048, 256, 0, stream>>>(q, k, v, Wi, bi, Wf, bf, ipre, fpre);
  scan_kernel<<<16, 256, 0, stream>>>(ipre, fpre, garr, Marr, bsum, Gt);
  convert_kernel<<<dim3(16, 16), 256, 0, stream>>>(k, v, kh, vt);
  attn_kernel<<<dim3(16, 16), 512, 0, stream>>>(q, kh, vt, garr, Marr, bsum, Gt,
                                                ln_w, ln_b, (float*)d_out);
}